// Round 14
// baseline (144.222 us; speedup 1.0000x reference)
//
#include <hip/hip_runtime.h>

typedef __bf16 bf16x8 __attribute__((ext_vector_type(8)));
typedef __bf16 bf16x4 __attribute__((ext_vector_type(4)));
typedef float f32x4 __attribute__((ext_vector_type(4)));

__device__ __forceinline__ void async_copy16(const void* g, void* l) {
    __builtin_amdgcn_global_load_lds(
        (const __attribute__((address_space(1))) void*)g,
        (__attribute__((address_space(3))) void*)l, 16, 0, 0);
}

// ---------------- cvt: x -> bf16, [Wq;Wk] -> bf16, [bq;bk] -> f32 ----------
__global__ __launch_bounds__(256) void k_cvt(
    const float4* __restrict__ x, const float4* __restrict__ Wq,
    const float4* __restrict__ Wk, const float4* __restrict__ bq,
    const float4* __restrict__ bk,
    bf16x4* __restrict__ xb, bf16x4* __restrict__ Wb,
    float4* __restrict__ biasc) {
    int i = blockIdx.x * 256 + threadIdx.x;
    if (i < 2097152) {
        float4 v = x[i];
        bf16x4 r = {(__bf16)v.x, (__bf16)v.y, (__bf16)v.z, (__bf16)v.w};
        xb[i] = r;
    }
    if (i < 131072) {
        float4 v = (i < 65536) ? Wq[i] : Wk[i - 65536];
        bf16x4 r = {(__bf16)v.x, (__bf16)v.y, (__bf16)v.z, (__bf16)v.w};
        Wb[i] = r;
    }
    if (i < 256) biasc[i] = (i < 128) ? bq[i] : bk[i - 128];
}

// ---------------- fold (r5-verified) ---------------------------------------
__global__ __launch_bounds__(256) void k_fold(
    const __bf16* __restrict__ xb, const float* __restrict__ Z,
    ushort* __restrict__ xzT) {
    __shared__ float tile[64][65];
    __shared__ float zin[64];
    const int b = blockIdx.y;
    const int td = blockIdx.x & 7;
    const int tn = blockIdx.x >> 3;
    const int n0 = tn * 64, d0 = td * 64;
    const int t = threadIdx.x;
    if (t < 64) zin[t] = 1.0f / Z[b * 2048 + n0 + t];
    __syncthreads();
    const int cl = t & 15, c4 = cl * 4, rr = t >> 4;
#pragma unroll
    for (int j = 0; j < 4; ++j) {
        int nr = rr + j * 16;
        bf16x4 v = *(const bf16x4*)&xb[((size_t)b * 2048 + n0 + nr) * 512 + d0 + c4];
        tile[nr][c4 + 0] = (float)v[0];
        tile[nr][c4 + 1] = (float)v[1];
        tile[nr][c4 + 2] = (float)v[2];
        tile[nr][c4 + 3] = (float)v[3];
    }
    __syncthreads();
#pragma unroll
    for (int j2 = 0; j2 < 4; ++j2) {
        int dr = rr + j2 * 16;
        bf16x4 pk;
#pragma unroll
        for (int j = 0; j < 4; ++j)
            pk[j] = (__bf16)(tile[j * 16 + cl][dr] * zin[c4 + j]);
        *(bf16x4*)&xzT[((size_t)b * 512 + d0 + dr) * 2048 + n0 + c4] = pk;
    }
}

// ===== 8-phase 256x256 bt-GEMM (r11 core, frozen; b/tm/tn from caller) =====
// EPI 1 uses nontemporal E stores (protect per-XCD L2 working set).
template <int EPI>
__device__ __forceinline__ void gemm8p(
    const ushort* __restrict__ A, int lda, long sA,
    const ushort* __restrict__ B, int ldb, long sB,
    ushort* __restrict__ C, int ldc, long sC,
    int b, int tm, int tn, int K,
    const float* __restrict__ bias, float scale2,
    float* __restrict__ Z, long sZ) {
    extern __shared__ char lds[];  // 128 KB: A regions @0, B regions @65536
    A += (size_t)b * sA;
    B += (size_t)b * sB;
    const int t = threadIdx.x;
    const int l = t & 63, w = t >> 6;
    const int wr = w >> 2, wc = w & 3;   // 2 x 4 waves, wave tile 128 x 64
    const int l15 = l & 15, g16 = l >> 4;

    size_t gAo[2], gBo[2];
    int dst[2];
#pragma unroll
    for (int p = 0; p < 2; ++p) {
        int off = p * 8192 + t * 16;
        int P = off >> 7, sl = (off >> 4) & 7;
        int u = sl ^ (P & 7);
        int rg = 2 * P + (u >> 2);
        int kb8 = (u & 3) * 8;
        gAo[p] = (size_t)(tm * 256 + rg) * lda + kb8;
        gBo[p] = (size_t)(tn * 256 + rg) * ldb + kb8;
        dst[p] = off;
    }

#define REG_A(d, ks) (((d) * 2 + (ks)) * 16384)
#define REG_B(d, ks) (65536 + ((d) * 2 + (ks)) * 16384)
#define STG_A(d, ks, kk)                                              \
    { int ro = REG_A(d, ks);                                          \
      async_copy16(A + gAo[0] + (kk), lds + ro + dst[0]);             \
      async_copy16(A + gAo[1] + (kk), lds + ro + dst[1]); }
#define STG_B(d, ks, kk)                                              \
    { int ro = REG_B(d, ks);                                          \
      async_copy16(B + gBo[0] + (kk), lds + ro + dst[0]);             \
      async_copy16(B + gBo[1] + (kk), lds + ro + dst[1]); }

    auto rdoff = [&](int row) {
        int P = row >> 1;
        int slot = (((row & 1) << 2) | g16) ^ (P & 7);
        return P * 128 + slot * 16;
    };

    f32x4 acc[8][4];
#pragma unroll
    for (int i = 0; i < 8; ++i)
#pragma unroll
        for (int j = 0; j < 4; ++j) acc[i][j] = (f32x4){0.f, 0.f, 0.f, 0.f};

    bf16x8 af[4], bg[4];

#define RD_B(d, ks)                                                   \
    _Pragma("unroll") for (int j = 0; j < 4; ++j)                     \
        bg[j] = *(const bf16x8*)(lds + REG_B(d, ks) +                 \
                                 rdoff(wc * 64 + j * 16 + l15));
#define RD_A(d, ks, isub)                                             \
    _Pragma("unroll") for (int i = 0; i < 4; ++i)                     \
        af[i] = *(const bf16x8*)(lds + REG_A(d, ks) +                 \
                                 rdoff(wr * 128 + (isub) * 64 + i * 16 + l15));
#define DO_MFMA(isub)                                                 \
    __builtin_amdgcn_s_setprio(1);                                    \
    _Pragma("unroll") for (int i = 0; i < 4; ++i)                     \
        _Pragma("unroll") for (int j = 0; j < 4; ++j)                 \
            acc[(isub) * 4 + i][j] = __builtin_amdgcn_mfma_f32_16x16x32_bf16( \
                af[i], bg[j], acc[(isub) * 4 + i][j], 0, 0, 0);       \
    __builtin_amdgcn_s_setprio(0);
#define BAR1(vm)                                                      \
    __builtin_amdgcn_sched_barrier(0);                                \
    __builtin_amdgcn_s_barrier();                                     \
    if (vm) { asm volatile("s_waitcnt lgkmcnt(0) vmcnt(4)" ::: "memory"); } \
    else    { asm volatile("s_waitcnt lgkmcnt(0)" ::: "memory"); }    \
    __builtin_amdgcn_sched_barrier(0);
#define BAR2                                                          \
    __builtin_amdgcn_s_barrier();                                     \
    asm volatile("" ::: "memory");                                    \
    __builtin_amdgcn_sched_barrier(0);

    STG_B(0, 0, 0); STG_A(0, 0, 0);
    STG_B(0, 1, 32); STG_A(0, 1, 32);
    STG_B(1, 0, 64); STG_A(1, 0, 64);
    asm volatile("s_waitcnt vmcnt(4)" ::: "memory");
    __builtin_amdgcn_s_barrier();
    asm volatile("" ::: "memory");

    const int NI = K >> 7;
    for (int it = 0; it < NI; ++it) {
        const int kb = it << 7;
        const int kn = (it + 1 < NI) ? (kb + 128) : kb;
        RD_B(0, 0); RD_A(0, 0, 0); STG_B(1, 1, kb + 96);
        BAR1(false); DO_MFMA(0); BAR2;
        RD_A(0, 0, 1); STG_A(1, 1, kb + 96);
        BAR1(false); DO_MFMA(1); BAR2;
        RD_B(0, 1); RD_A(0, 1, 0); STG_B(0, 0, kn);
        BAR1(false); DO_MFMA(0); BAR2;
        RD_A(0, 1, 1); STG_A(0, 0, kn);
        BAR1(true); DO_MFMA(1); BAR2;
        RD_B(1, 0); RD_A(1, 0, 0); STG_B(0, 1, kn + 32);
        BAR1(false); DO_MFMA(0); BAR2;
        RD_A(1, 0, 1); STG_A(0, 1, kn + 32);
        BAR1(false); DO_MFMA(1); BAR2;
        RD_B(1, 1); RD_A(1, 1, 0); STG_B(1, 0, kn + 64);
        BAR1(false); DO_MFMA(0); BAR2;
        RD_A(1, 1, 1); STG_A(1, 0, kn + 64);
        BAR1(true); DO_MFMA(1); BAR2;
    }
    asm volatile("s_waitcnt vmcnt(0)" ::: "memory");

    const int mb = tm * 256 + wr * 128;
    const int nb = tn * 256 + wc * 64;
    const int cl = l15;
    ushort* Cp = C + (size_t)b * sC;

    if (EPI == 0) {
#pragma unroll
        for (int i = 0; i < 8; ++i)
#pragma unroll
            for (int q = 0; q < 4; ++q) {
                int row = mb + i * 16 + (l >> 4) * 4 + q;
                bf16x4 pk;
#pragma unroll
                for (int j = 0; j < 4; ++j)
                    pk[j] = (__bf16)(acc[i][j][q] + bias[nb + j * 16 + cl]);
                *(bf16x4*)&Cp[(size_t)row * ldc + nb + cl * 4] = pk;
            }
    } else {
        float colsum[4] = {0.f, 0.f, 0.f, 0.f};
#pragma unroll
        for (int i = 0; i < 8; ++i)
#pragma unroll
            for (int q = 0; q < 4; ++q) {
                int row = mb + i * 16 + (l >> 4) * 4 + q;
                bf16x4 pk;
#pragma unroll
                for (int j = 0; j < 4; ++j) {
                    float e = __builtin_amdgcn_exp2f(acc[i][j][q] * scale2);
                    colsum[j] += e;
                    pk[j] = (__bf16)e;
                }
                __builtin_nontemporal_store(
                    pk, (bf16x4*)&Cp[(size_t)row * ldc + nb + cl * 4]);
            }
#pragma unroll
        for (int j = 0; j < 4; ++j) {
            float s = colsum[j];
            s += __shfl_xor(s, 16);
            s += __shfl_xor(s, 32);
            if (l < 16) atomicAdd(&Z[b * sZ + nb + l * 4 + j], s);
        }
    }
#undef REG_A
#undef REG_B
#undef STG_A
#undef STG_B
#undef RD_A
#undef RD_B
#undef DO_MFMA
#undef BAR1
#undef BAR2
}

// proj: 256 blocks = 64 tm x 4 tn (r13 map).
__global__ __launch_bounds__(512, 2) void k_proj8(
    const ushort* __restrict__ A, const ushort* __restrict__ B,
    ushort* __restrict__ C, const float* __restrict__ bias) {
    const int bx = blockIdx.x, p = bx & 7, j = bx >> 3;  // j 0..31
    const int tm = p * 8 + (j >> 2), tn = j & 3;
    gemm8p<0>(A, 512, 0L, B, 512, 0L, C, 1024, 0L,
              0, tm, tn, 512, bias, 0.f, nullptr, 0L);
}

// escore: 1-D grid 512, batch = bx&7 -> XCD p serves batch p only.
// Per-XCD working set = q+k of one batch = 4 MB = L2. E writes are nt.
__global__ __launch_bounds__(512, 2) void k_escore8(
    const ushort* __restrict__ A, const ushort* __restrict__ B,
    ushort* __restrict__ C, float* __restrict__ Z) {
    const int bx = blockIdx.x;
    const int b = bx & 7, tile = bx >> 3;   // tile 0..63
    const int tm = tile & 7, tn = tile >> 3;
    gemm8p<1>(A, 1024, 2048L * 1024, B, 1024, 2048L * 1024,
              C, 2048, 2048L * 2048, b, tm, tn, 512,
              nullptr, 0.063758716f, Z, 2048L);
}

// ===== k_out: r8 2-deep counted-vmcnt 128x128 core; r13 map (frozen) =======
__global__ __launch_bounds__(256) void k_out(
    const ushort* __restrict__ Ain, const ushort* __restrict__ Bin,
    float* __restrict__ Cout) {
    __shared__ ushort lA[2][8192];
    __shared__ ushort lB[2][8192];
    const int lda = 2048, ldb = 2048, ldc = 512, K = 2048;
    const int b = blockIdx.y;
    const ushort* A = Ain + (size_t)b * 2048L * 2048;
    const ushort* B = Bin + (size_t)b * 512L * 2048;
    const int bx = blockIdx.x, p = bx & 7, j = bx >> 3;  // j 0..7
    const int tm = 2 * p + (j >> 2), tn = j & 3;
    const int t = threadIdx.x;
    const int l = t & 63, w = t >> 6;
    const int wr = w >> 1, wc = w & 1;

    size_t gA[4], gB[4];
    int dOf[4];
#pragma unroll
    for (int q = 0; q < 4; ++q) {
        int off = q * 4096 + t * 16;
        int row = off >> 7, kb = off & 127;
        int kswz = kb ^ ((row & 7) << 4);
        gA[q] = (size_t)(tm * 128 + row) * lda + (kswz >> 1);
        gB[q] = (size_t)(tn * 128 + row) * ldb + (kswz >> 1);
        dOf[q] = off;
    }
    auto stage = [&](int buf, int k0) {
#pragma unroll
        for (int q = 0; q < 4; ++q) {
            async_copy16(A + gA[q] + k0, (char*)lA[buf] + dOf[q]);
            async_copy16(B + gB[q] + k0, (char*)lB[buf] + dOf[q]);
        }
    };

    f32x4 acc[4][4];
#pragma unroll
    for (int i = 0; i < 4; ++i)
#pragma unroll
        for (int j2 = 0; j2 < 4; ++j2) acc[i][j2] = (f32x4){0.f, 0.f, 0.f, 0.f};

    const int nk = K >> 6;
    stage(0, 0);
    stage(1, 64);
    asm volatile("s_waitcnt vmcnt(8)" ::: "memory");
    __builtin_amdgcn_s_barrier();
    asm volatile("" ::: "memory");

    for (int kt = 0; kt < nk; ++kt) {
        const int cur = kt & 1;
        bf16x8 af[4][2], bg[4][2];
#pragma unroll
        for (int ks = 0; ks < 2; ++ks)
#pragma unroll
            for (int i = 0; i < 4; ++i) {
                int rowA = wr * 64 + i * 16 + (l & 15);
                int colA = (ks * 64 + (l >> 4) * 16) ^ ((rowA & 7) << 4);
                af[i][ks] = *(const bf16x8*)((const char*)lA[cur] + rowA * 128 + colA);
                int rowB = wc * 64 + i * 16 + (l & 15);
                int colB = (ks * 64 + (l >> 4) * 16) ^ ((rowB & 7) << 4);
                bg[i][ks] = *(const bf16x8*)((const char*)lB[cur] + rowB * 128 + colB);
            }
        asm volatile("s_waitcnt lgkmcnt(0)" ::: "memory");
        __builtin_amdgcn_sched_barrier(0);
        __builtin_amdgcn_s_barrier();
        asm volatile("" ::: "memory");
        if (kt + 2 < nk) stage(cur, (kt + 2) << 6);
        __builtin_amdgcn_sched_barrier(0);
        __builtin_amdgcn_s_setprio(1);
#pragma unroll
        for (int ks = 0; ks < 2; ++ks)
#pragma unroll
            for (int i = 0; i < 4; ++i)
#pragma unroll
                for (int j2 = 0; j2 < 4; ++j2)
                    acc[i][j2] = __builtin_amdgcn_mfma_f32_16x16x32_bf16(
                        af[i][ks], bg[j2][ks], acc[i][j2], 0, 0, 0);
        __builtin_amdgcn_s_setprio(0);
        if (kt + 2 < nk) {
            asm volatile("s_waitcnt vmcnt(8)" ::: "memory");
        } else {
            asm volatile("s_waitcnt vmcnt(0)" ::: "memory");
        }
        __builtin_amdgcn_s_barrier();
        asm volatile("" ::: "memory");
    }

    const int mb = tm * 128 + wr * 64;
    const int nb = tn * 128 + wc * 64;
    float* Cp = Cout + (size_t)b * 2048L * 512;
#pragma unroll
    for (int i = 0; i < 4; ++i)
#pragma unroll
        for (int j2 = 0; j2 < 4; ++j2)
#pragma unroll
            for (int q = 0; q < 4; ++q) {
                int row = mb + i * 16 + (l >> 4) * 4 + q;
                int col = nb + j2 * 16 + (l & 15);
                Cp[(size_t)row * ldc + col] = acc[i][j2][q];
            }
}

namespace {
struct AttrInit {
    AttrInit() {
        hipFuncSetAttribute(reinterpret_cast<const void*>(&k_proj8),
                            hipFuncAttributeMaxDynamicSharedMemorySize, 131072);
        hipFuncSetAttribute(reinterpret_cast<const void*>(&k_escore8),
                            hipFuncAttributeMaxDynamicSharedMemorySize, 131072);
    }
};
AttrInit attr_init_;
}

extern "C" void kernel_launch(void* const* d_in, const int* in_sizes, int n_in,
                              void* d_out, int out_size, void* d_ws, size_t ws_size,
                              hipStream_t stream) {
    const float* x  = (const float*)d_in[0];
    const float* Wq = (const float*)d_in[1];
    const float* bq = (const float*)d_in[2];
    const float* Wk = (const float*)d_in[3];
    const float* bk = (const float*)d_in[4];

    char* ws = (char*)d_ws;
    ushort* xb    = (ushort*)(ws);                 // 16 MB
    ushort* Wb    = (ushort*)(ws + 16777216);      //  1 MB
    float*  biasc = (float*) (ws + 17825792);      //  4 KB
    float*  Z     = (float*) (ws + 17829888);      // 64 KB (storage-indexed)
    ushort* qkb   = (ushort*)(ws + 17895424);      // 32 MB (reused as xzT)
    ushort* E     = (ushort*)(ws + 51449856);      // 64 MB
    ushort* xzT   = qkb;

    (void)hipMemsetAsync(Z, 0, 16384 * 4, stream);

    k_cvt<<<8192, 256, 0, stream>>>(
        (const float4*)x, (const float4*)Wq, (const float4*)Wk,
        (const float4*)bq, (const float4*)bk,
        (bf16x4*)xb, (bf16x4*)Wb, (float4*)biasc);

    // proj: qk[m, P(h)] = x . W^T + bias  (M=16384, N=1024, K=512)
    k_proj8<<<dim3(256, 1), 512, 131072, stream>>>(xb, Wb, qkb, biasc);

    // E-pass: batch->XCD mapped 1-D grid; nt E stores
    k_escore8<<<dim3(512), 512, 131072, stream>>>(qkb + 512, qkb, E, Z);

    // fold: xzT[b][d][s] = bf16(x[b][Q(s)][d] / Z_s[s])
    k_fold<<<dim3(256, 8), 256, 0, stream>>>((const __bf16*)xb, Z, xzT);

    // out: out[b][m][d] = sum_s E[b][m][s] * xzT[b][d][s]   (fp32)
    k_out<<<dim3(64, 8), 256, 0, stream>>>(E, xzT, (float*)d_out);
}

// Round 15
// 123.958 us; speedup vs baseline: 1.1635x; 1.1635x over previous
//
#include <hip/hip_runtime.h>

typedef __bf16 bf16x8 __attribute__((ext_vector_type(8)));
typedef __bf16 bf16x4 __attribute__((ext_vector_type(4)));
typedef float f32x4 __attribute__((ext_vector_type(4)));

__device__ __forceinline__ void async_copy16(const void* g, void* l) {
    __builtin_amdgcn_global_load_lds(
        (const __attribute__((address_space(1))) void*)g,
        (__attribute__((address_space(3))) void*)l, 16, 0, 0);
}

// ---------------- cvt: x -> bf16, [Wq;Wk] -> bf16, bias concat, Z zero -----
__global__ __launch_bounds__(256) void k_cvt(
    const float4* __restrict__ x, const float4* __restrict__ Wq,
    const float4* __restrict__ Wk, const float4* __restrict__ bq,
    const float4* __restrict__ bk,
    bf16x4* __restrict__ xb, bf16x4* __restrict__ Wb,
    float4* __restrict__ biasc, float4* __restrict__ Z) {
    int i = blockIdx.x * 256 + threadIdx.x;
    if (i < 2097152) {
        float4 v = x[i];
        bf16x4 r = {(__bf16)v.x, (__bf16)v.y, (__bf16)v.z, (__bf16)v.w};
        xb[i] = r;
    }
    if (i < 131072) {
        float4 v = (i < 65536) ? Wq[i] : Wk[i - 65536];
        bf16x4 r = {(__bf16)v.x, (__bf16)v.y, (__bf16)v.z, (__bf16)v.w};
        Wb[i] = r;
    }
    if (i < 256) biasc[i] = (i < 128) ? bq[i] : bk[i - 128];
    if (i < 4096) Z[i] = (float4){0.f, 0.f, 0.f, 0.f};
}

// ---------------- fold (r5-verified) ---------------------------------------
__global__ __launch_bounds__(256) void k_fold(
    const __bf16* __restrict__ xb, const float* __restrict__ Z,
    ushort* __restrict__ xzT) {
    __shared__ float tile[64][65];
    __shared__ float zin[64];
    const int b = blockIdx.y;
    const int td = blockIdx.x & 7;
    const int tn = blockIdx.x >> 3;
    const int n0 = tn * 64, d0 = td * 64;
    const int t = threadIdx.x;
    if (t < 64) zin[t] = 1.0f / Z[b * 2048 + n0 + t];
    __syncthreads();
    const int cl = t & 15, c4 = cl * 4, rr = t >> 4;
#pragma unroll
    for (int j = 0; j < 4; ++j) {
        int nr = rr + j * 16;
        bf16x4 v = *(const bf16x4*)&xb[((size_t)b * 2048 + n0 + nr) * 512 + d0 + c4];
        tile[nr][c4 + 0] = (float)v[0];
        tile[nr][c4 + 1] = (float)v[1];
        tile[nr][c4 + 2] = (float)v[2];
        tile[nr][c4 + 3] = (float)v[3];
    }
    __syncthreads();
#pragma unroll
    for (int j2 = 0; j2 < 4; ++j2) {
        int dr = rr + j2 * 16;
        bf16x4 pk;
#pragma unroll
        for (int j = 0; j < 4; ++j)
            pk[j] = (__bf16)(tile[j * 16 + cl][dr] * zin[c4 + j]);
        *(bf16x4*)&xzT[((size_t)b * 512 + d0 + dr) * 2048 + n0 + c4] = pk;
    }
}

// ===== 8-phase 256x256 bt-GEMM (r11 core, frozen; b/tm/tn from caller) =====
template <int EPI>
__device__ __forceinline__ void gemm8p(
    const ushort* __restrict__ A, int lda, long sA,
    const ushort* __restrict__ B, int ldb, long sB,
    ushort* __restrict__ C, int ldc, long sC,
    int b, int tm, int tn, int K,
    const float* __restrict__ bias, float scale2,
    float* __restrict__ Z, long sZ) {
    extern __shared__ char lds[];  // 128 KB: A regions @0, B regions @65536
    A += (size_t)b * sA;
    B += (size_t)b * sB;
    const int t = threadIdx.x;
    const int l = t & 63, w = t >> 6;
    const int wr = w >> 2, wc = w & 3;   // 2 x 4 waves, wave tile 128 x 64
    const int l15 = l & 15, g16 = l >> 4;

    size_t gAo[2], gBo[2];
    int dst[2];
#pragma unroll
    for (int p = 0; p < 2; ++p) {
        int off = p * 8192 + t * 16;
        int P = off >> 7, sl = (off >> 4) & 7;
        int u = sl ^ (P & 7);
        int rg = 2 * P + (u >> 2);
        int kb8 = (u & 3) * 8;
        gAo[p] = (size_t)(tm * 256 + rg) * lda + kb8;
        gBo[p] = (size_t)(tn * 256 + rg) * ldb + kb8;
        dst[p] = off;
    }

#define REG_A(d, ks) (((d) * 2 + (ks)) * 16384)
#define REG_B(d, ks) (65536 + ((d) * 2 + (ks)) * 16384)
#define STG_A(d, ks, kk)                                              \
    { int ro = REG_A(d, ks);                                          \
      async_copy16(A + gAo[0] + (kk), lds + ro + dst[0]);             \
      async_copy16(A + gAo[1] + (kk), lds + ro + dst[1]); }
#define STG_B(d, ks, kk)                                              \
    { int ro = REG_B(d, ks);                                          \
      async_copy16(B + gBo[0] + (kk), lds + ro + dst[0]);             \
      async_copy16(B + gBo[1] + (kk), lds + ro + dst[1]); }

    auto rdoff = [&](int row) {
        int P = row >> 1;
        int slot = (((row & 1) << 2) | g16) ^ (P & 7);
        return P * 128 + slot * 16;
    };

    f32x4 acc[8][4];
#pragma unroll
    for (int i = 0; i < 8; ++i)
#pragma unroll
        for (int j = 0; j < 4; ++j) acc[i][j] = (f32x4){0.f, 0.f, 0.f, 0.f};

    bf16x8 af[4], bg[4];

#define RD_B(d, ks)                                                   \
    _Pragma("unroll") for (int j = 0; j < 4; ++j)                     \
        bg[j] = *(const bf16x8*)(lds + REG_B(d, ks) +                 \
                                 rdoff(wc * 64 + j * 16 + l15));
#define RD_A(d, ks, isub)                                             \
    _Pragma("unroll") for (int i = 0; i < 4; ++i)                     \
        af[i] = *(const bf16x8*)(lds + REG_A(d, ks) +                 \
                                 rdoff(wr * 128 + (isub) * 64 + i * 16 + l15));
#define DO_MFMA(isub)                                                 \
    __builtin_amdgcn_s_setprio(1);                                    \
    _Pragma("unroll") for (int i = 0; i < 4; ++i)                     \
        _Pragma("unroll") for (int j = 0; j < 4; ++j)                 \
            acc[(isub) * 4 + i][j] = __builtin_amdgcn_mfma_f32_16x16x32_bf16( \
                af[i], bg[j], acc[(isub) * 4 + i][j], 0, 0, 0);       \
    __builtin_amdgcn_s_setprio(0);
#define BAR1(vm)                                                      \
    __builtin_amdgcn_sched_barrier(0);                                \
    __builtin_amdgcn_s_barrier();                                     \
    if (vm) { asm volatile("s_waitcnt lgkmcnt(0) vmcnt(4)" ::: "memory"); } \
    else    { asm volatile("s_waitcnt lgkmcnt(0)" ::: "memory"); }    \
    __builtin_amdgcn_sched_barrier(0);
#define BAR2                                                          \
    __builtin_amdgcn_s_barrier();                                     \
    asm volatile("" ::: "memory");                                    \
    __builtin_amdgcn_sched_barrier(0);

    STG_B(0, 0, 0); STG_A(0, 0, 0);
    STG_B(0, 1, 32); STG_A(0, 1, 32);
    STG_B(1, 0, 64); STG_A(1, 0, 64);
    asm volatile("s_waitcnt vmcnt(4)" ::: "memory");
    __builtin_amdgcn_s_barrier();
    asm volatile("" ::: "memory");

    const int NI = K >> 7;
    for (int it = 0; it < NI; ++it) {
        const int kb = it << 7;
        const int kn = (it + 1 < NI) ? (kb + 128) : kb;
        RD_B(0, 0); RD_A(0, 0, 0); STG_B(1, 1, kb + 96);
        BAR1(false); DO_MFMA(0); BAR2;
        RD_A(0, 0, 1); STG_A(1, 1, kb + 96);
        BAR1(false); DO_MFMA(1); BAR2;
        RD_B(0, 1); RD_A(0, 1, 0); STG_B(0, 0, kn);
        BAR1(false); DO_MFMA(0); BAR2;
        RD_A(0, 1, 1); STG_A(0, 0, kn);
        BAR1(true); DO_MFMA(1); BAR2;
        RD_B(1, 0); RD_A(1, 0, 0); STG_B(0, 1, kn + 32);
        BAR1(false); DO_MFMA(0); BAR2;
        RD_A(1, 0, 1); STG_A(0, 1, kn + 32);
        BAR1(false); DO_MFMA(1); BAR2;
        RD_B(1, 1); RD_A(1, 1, 0); STG_B(1, 0, kn + 64);
        BAR1(false); DO_MFMA(0); BAR2;
        RD_A(1, 1, 1); STG_A(1, 0, kn + 64);
        BAR1(true); DO_MFMA(1); BAR2;
    }
    asm volatile("s_waitcnt vmcnt(0)" ::: "memory");

    const int mb = tm * 256 + wr * 128;
    const int nb = tn * 256 + wc * 64;
    const int cl = l15;
    ushort* Cp = C + (size_t)b * sC;

    if (EPI == 0) {
#pragma unroll
        for (int i = 0; i < 8; ++i)
#pragma unroll
            for (int q = 0; q < 4; ++q) {
                int row = mb + i * 16 + (l >> 4) * 4 + q;
                bf16x4 pk;
#pragma unroll
                for (int j = 0; j < 4; ++j)
                    pk[j] = (__bf16)(acc[i][j][q] + bias[nb + j * 16 + cl]);
                *(bf16x4*)&Cp[(size_t)row * ldc + nb + cl * 4] = pk;
            }
    } else {
        float colsum[4] = {0.f, 0.f, 0.f, 0.f};
#pragma unroll
        for (int i = 0; i < 8; ++i)
#pragma unroll
            for (int q = 0; q < 4; ++q) {
                int row = mb + i * 16 + (l >> 4) * 4 + q;
                bf16x4 pk;
#pragma unroll
                for (int j = 0; j < 4; ++j) {
                    float e = __builtin_amdgcn_exp2f(acc[i][j][q] * scale2);
                    colsum[j] += e;
                    pk[j] = (__bf16)e;
                }
                *(bf16x4*)&Cp[(size_t)row * ldc + nb + cl * 4] = pk;
            }
#pragma unroll
        for (int j = 0; j < 4; ++j) {
            float s = colsum[j];
            s += __shfl_xor(s, 16);
            s += __shfl_xor(s, 32);
            if (l < 16) atomicAdd(&Z[b * sZ + nb + l * 4 + j], s);
        }
    }
#undef REG_A
#undef REG_B
#undef STG_A
#undef STG_B
#undef RD_A
#undef RD_B
#undef DO_MFMA
#undef BAR1
#undef BAR2
}

// proj: 256 blocks = 64 tm x 4 tn (r13 map).
__global__ __launch_bounds__(512, 2) void k_proj8(
    const ushort* __restrict__ A, const ushort* __restrict__ B,
    ushort* __restrict__ C, const float* __restrict__ bias) {
    const int bx = blockIdx.x, p = bx & 7, j = bx >> 3;  // j 0..31
    const int tm = p * 8 + (j >> 2), tn = j & 3;
    gemm8p<0>(A, 512, 0L, B, 512, 0L, C, 1024, 0L,
              0, tm, tn, 512, bias, 0.f, nullptr, 0L);
}

// escore: 1-D grid 512, batch = bx&7 -> XCD p serves batch p only.
// Per-XCD working set = q+k of one batch = 4 MB = L2. (normal stores:
// E must flow through L2/L3 for k_out to read it back at cache BW — r14
// proved nt stores cost +17 us downstream.)
__global__ __launch_bounds__(512, 2) void k_escore8(
    const ushort* __restrict__ A, const ushort* __restrict__ B,
    ushort* __restrict__ C, float* __restrict__ Z) {
    const int bx = blockIdx.x;
    const int b = bx & 7, tile = bx >> 3;   // tile 0..63
    const int tm = tile & 7, tn = tile >> 3;
    gemm8p<1>(A, 1024, 2048L * 1024, B, 1024, 2048L * 1024,
              C, 2048, 2048L * 2048, b, tm, tn, 512,
              nullptr, 0.063758716f, Z, 2048L);
}

// ===== k_out: r8 2-deep counted-vmcnt 128x128 core; r13 map (frozen) =======
__global__ __launch_bounds__(256) void k_out(
    const ushort* __restrict__ Ain, const ushort* __restrict__ Bin,
    float* __restrict__ Cout) {
    __shared__ ushort lA[2][8192];
    __shared__ ushort lB[2][8192];
    const int lda = 2048, ldb = 2048, ldc = 512, K = 2048;
    const int b = blockIdx.y;
    const ushort* A = Ain + (size_t)b * 2048L * 2048;
    const ushort* B = Bin + (size_t)b * 512L * 2048;
    const int bx = blockIdx.x, p = bx & 7, j = bx >> 3;  // j 0..7
    const int tm = 2 * p + (j >> 2), tn = j & 3;
    const int t = threadIdx.x;
    const int l = t & 63, w = t >> 6;
    const int wr = w >> 1, wc = w & 1;

    size_t gA[4], gB[4];
    int dOf[4];
#pragma unroll
    for (int q = 0; q < 4; ++q) {
        int off = q * 4096 + t * 16;
        int row = off >> 7, kb = off & 127;
        int kswz = kb ^ ((row & 7) << 4);
        gA[q] = (size_t)(tm * 128 + row) * lda + (kswz >> 1);
        gB[q] = (size_t)(tn * 128 + row) * ldb + (kswz >> 1);
        dOf[q] = off;
    }
    auto stage = [&](int buf, int k0) {
#pragma unroll
        for (int q = 0; q < 4; ++q) {
            async_copy16(A + gA[q] + k0, (char*)lA[buf] + dOf[q]);
            async_copy16(B + gB[q] + k0, (char*)lB[buf] + dOf[q]);
        }
    };

    f32x4 acc[4][4];
#pragma unroll
    for (int i = 0; i < 4; ++i)
#pragma unroll
        for (int j2 = 0; j2 < 4; ++j2) acc[i][j2] = (f32x4){0.f, 0.f, 0.f, 0.f};

    const int nk = K >> 6;
    stage(0, 0);
    stage(1, 64);
    asm volatile("s_waitcnt vmcnt(8)" ::: "memory");
    __builtin_amdgcn_s_barrier();
    asm volatile("" ::: "memory");

    for (int kt = 0; kt < nk; ++kt) {
        const int cur = kt & 1;
        bf16x8 af[4][2], bg[4][2];
#pragma unroll
        for (int ks = 0; ks < 2; ++ks)
#pragma unroll
            for (int i = 0; i < 4; ++i) {
                int rowA = wr * 64 + i * 16 + (l & 15);
                int colA = (ks * 64 + (l >> 4) * 16) ^ ((rowA & 7) << 4);
                af[i][ks] = *(const bf16x8*)((const char*)lA[cur] + rowA * 128 + colA);
                int rowB = wc * 64 + i * 16 + (l & 15);
                int colB = (ks * 64 + (l >> 4) * 16) ^ ((rowB & 7) << 4);
                bg[i][ks] = *(const bf16x8*)((const char*)lB[cur] + rowB * 128 + colB);
            }
        asm volatile("s_waitcnt lgkmcnt(0)" ::: "memory");
        __builtin_amdgcn_sched_barrier(0);
        __builtin_amdgcn_s_barrier();
        asm volatile("" ::: "memory");
        if (kt + 2 < nk) stage(cur, (kt + 2) << 6);
        __builtin_amdgcn_sched_barrier(0);
        __builtin_amdgcn_s_setprio(1);
#pragma unroll
        for (int ks = 0; ks < 2; ++ks)
#pragma unroll
            for (int i = 0; i < 4; ++i)
#pragma unroll
                for (int j2 = 0; j2 < 4; ++j2)
                    acc[i][j2] = __builtin_amdgcn_mfma_f32_16x16x32_bf16(
                        af[i][ks], bg[j2][ks], acc[i][j2], 0, 0, 0);
        __builtin_amdgcn_s_setprio(0);
        if (kt + 2 < nk) {
            asm volatile("s_waitcnt vmcnt(8)" ::: "memory");
        } else {
            asm volatile("s_waitcnt vmcnt(0)" ::: "memory");
        }
        __builtin_amdgcn_s_barrier();
        asm volatile("" ::: "memory");
    }

    const int mb = tm * 128 + wr * 64;
    const int nb = tn * 128 + wc * 64;
    float* Cp = Cout + (size_t)b * 2048L * 512;
#pragma unroll
    for (int i = 0; i < 4; ++i)
#pragma unroll
        for (int j2 = 0; j2 < 4; ++j2)
#pragma unroll
            for (int q = 0; q < 4; ++q) {
                int row = mb + i * 16 + (l >> 4) * 4 + q;
                int col = nb + j2 * 16 + (l & 15);
                Cp[(size_t)row * ldc + col] = acc[i][j2][q];
            }
}

namespace {
struct AttrInit {
    AttrInit() {
        hipFuncSetAttribute(reinterpret_cast<const void*>(&k_proj8),
                            hipFuncAttributeMaxDynamicSharedMemorySize, 131072);
        hipFuncSetAttribute(reinterpret_cast<const void*>(&k_escore8),
                            hipFuncAttributeMaxDynamicSharedMemorySize, 131072);
    }
};
AttrInit attr_init_;
}

extern "C" void kernel_launch(void* const* d_in, const int* in_sizes, int n_in,
                              void* d_out, int out_size, void* d_ws, size_t ws_size,
                              hipStream_t stream) {
    const float* x  = (const float*)d_in[0];
    const float* Wq = (const float*)d_in[1];
    const float* bq = (const float*)d_in[2];
    const float* Wk = (const float*)d_in[3];
    const float* bk = (const float*)d_in[4];

    char* ws = (char*)d_ws;
    ushort* xb    = (ushort*)(ws);                 // 16 MB
    ushort* Wb    = (ushort*)(ws + 16777216);      //  1 MB
    float*  biasc = (float*) (ws + 17825792);      //  4 KB
    float*  Z     = (float*) (ws + 17829888);      // 64 KB (storage-indexed)
    ushort* qkb   = (ushort*)(ws + 17895424);      // 32 MB (reused as xzT)
    ushort* E     = (ushort*)(ws + 51449856);      // 64 MB
    ushort* xzT   = qkb;

    // cvt also zeroes Z (memset dispatch removed)
    k_cvt<<<8192, 256, 0, stream>>>(
        (const float4*)x, (const float4*)Wq, (const float4*)Wk,
        (const float4*)bq, (const float4*)bk,
        (bf16x4*)xb, (bf16x4*)Wb, (float4*)biasc, (float4*)Z);

    // proj: qk[m, P(h)] = x . W^T + bias  (M=16384, N=1024, K=512)
    k_proj8<<<dim3(256, 1), 512, 131072, stream>>>(xb, Wb, qkb, biasc);

    // E-pass: batch->XCD mapped 1-D grid (normal stores)
    k_escore8<<<dim3(512), 512, 131072, stream>>>(qkb + 512, qkb, E, Z);

    // fold: xzT[b][d][s] = bf16(x[b][Q(s)][d] / Z_s[s])
    k_fold<<<dim3(256, 8), 256, 0, stream>>>((const __bf16*)xb, Z, xzT);

    // out: out[b][m][d] = sum_s E[b][m][s] * xzT[b][d][s]   (fp32)
    k_out<<<dim3(64, 8), 256, 0, stream>>>(E, xzT, (float*)d_out);
}